// Round 9
// baseline (104.389 us; speedup 1.0000x reference)
//
#include <hip/hip_runtime.h>
#include <math.h>

#define TK 30
#define TH 128
#define TNIN 256
#define TDFF 512
#define NTOK 8000
#define ROWP 264   // KVs row stride in u16

typedef __attribute__((ext_vector_type(8))) short short8v;
typedef __attribute__((ext_vector_type(4))) short short4v;
typedef __attribute__((ext_vector_type(4))) float f32x4;

constexpr float LN_EPS = 1e-6f;
constexpr float NEG_INF = -3.402823466e38f;
constexpr float INV_SQRT_D = 0.17677669529663687f;  // 1/sqrt(32)

static __device__ __forceinline__ unsigned short f2bf(float f) {
  unsigned u = __float_as_uint(f);
  u = u + 0x7fffu + ((u >> 16) & 1u);
  return (unsigned short)(u >> 16);
}
static __device__ __forceinline__ float bf2f(unsigned short s) {
  return __uint_as_float(((unsigned)s) << 16);
}
static __device__ __forceinline__ void gload16(const void* gsrc, void* ldst) {
  __builtin_amdgcn_global_load_lds(
      (const __attribute__((address_space(1))) unsigned int*)gsrc,
      (__attribute__((address_space(3))) unsigned int*)ldst, 16, 0, 0);
}

// ---------------------------------------------------------------------------
// K0: weight prep. Frag-linear bf16 (verified pattern):
//   elem ((ks*NF + n)*64 + lane)*8 + j = W[n*16+(lane&15)][ks*32+(lane>>4)*8+j]
//  <  65536 : Wc2 = [W_K;W_V] (NF=16,K=256)
//  <  81920 : Wq2 = W_Q       (NF=8, K=128)
//  <  98304 : Wp2 = W_O       (NF=8, K=128)
//  < 163840 : Wi2 = W_in      (NF=32,K=128)
//  < 229376 : Wo2 = W_out     (NF=8, K=512)
// ---------------------------------------------------------------------------
__global__ void conv_weights_kernel(const float* __restrict__ W_K,
                                    const float* __restrict__ W_V,
                                    const float* __restrict__ W_Q,
                                    const float* __restrict__ W_O,
                                    const float* __restrict__ W_in,
                                    const float* __restrict__ W_out,
                                    unsigned short* __restrict__ Wc2,
                                    unsigned short* __restrict__ Wq2,
                                    unsigned short* __restrict__ Wp2,
                                    unsigned short* __restrict__ Wi2,
                                    unsigned short* __restrict__ Wo2)
{
  int idx = blockIdx.x * 256 + threadIdx.x;   // 0..229375
  if (idx < 65536) {
    int e = idx >> 3, j = idx & 7;
    int kk = e >> 10, n = (e >> 6) & 15, lane = e & 63;
    int r = n*16 + (lane & 15);
    int c = kk*32 + (lane >> 4)*8 + j;
    float v = (r < TH) ? W_K[(size_t)r*TNIN + c] : W_V[(size_t)(r-TH)*TNIN + c];
    Wc2[idx] = f2bf(v);
  } else if (idx < 81920) {
    int i2 = idx - 65536;
    int e = i2 >> 3, j = i2 & 7;
    int kk = e >> 9, n = (e >> 6) & 7, lane = e & 63;
    int r = n*16 + (lane & 15);
    int c = kk*32 + (lane >> 4)*8 + j;
    Wq2[i2] = f2bf(W_Q[(size_t)r*TH + c]);
  } else if (idx < 98304) {
    int ip = idx - 81920;
    int e = ip >> 3, j = ip & 7;
    int kk = e >> 9, n = (e >> 6) & 7, lane = e & 63;
    int r = n*16 + (lane & 15);
    int c = kk*32 + (lane >> 4)*8 + j;
    Wp2[ip] = f2bf(W_O[(size_t)r*TH + c]);
  } else if (idx < 163840) {
    int i3 = idx - 98304;
    int e = i3 >> 3, j = i3 & 7;
    int ks = e >> 11, n = (e >> 6) & 31, lane = e & 63;
    int r = n*16 + (lane & 15);
    int c = ks*32 + (lane >> 4)*8 + j;
    Wi2[i3] = f2bf(W_in[(size_t)r*TH + c]);
  } else {
    int i4 = idx - 163840;
    int e = i4 >> 3, j = i4 & 7;
    int ks = e >> 9, n = (e >> 6) & 7, lane = e & 63;
    int r = n*16 + (lane & 15);
    int c = ks*32 + (lane >> 4)*8 + j;
    Wo2[i4] = f2bf(W_out[(size_t)r*TDFF + c]);
  }
}

// ---------------------------------------------------------------------------
// K1: fused Q-proj + KV-GEMM + attention core.
// grid = 2000 x 512 thr, 2 blocks/CU. GEMM pipeline = R8 (audited schedule);
// W_Q fragments held in regs through the GEMM; Q computed post-loop via MFMA.
// ---------------------------------------------------------------------------
__global__ __launch_bounds__(512, 4) void kvattn_kernel(
    const float* __restrict__ A, const unsigned short* __restrict__ Wc2,
    const unsigned short* __restrict__ Wq2, const float* __restrict__ h_v,
    const float* __restrict__ mask_attend, float* __restrict__ ul)
{
  const int tid  = threadIdx.x;
  const int wave = tid >> 6;
  const int lane = tid & 63;
  const int lm   = lane & 15;
  const int lgp  = lane >> 4;
  const int mh   = wave >> 2;   // 0..1
  const int nq   = wave & 3;    // 0..3
  const int bn0  = blockIdx.x * 4;

  __shared__ __align__(16) char smem[73728];
  unsigned short* Bl  = (unsigned short*)smem;          // [3][8192]   0..49152
  unsigned short* Al  = (unsigned short*)(smem + 49152);// [2][128][40] ..69632
  unsigned short* KVs = (unsigned short*)smem;          // [128][264] overlay 0..67584
  float* att = (float*)(smem + 67584);                  // [4][4][32] (Al tail, dead)
  float* hvp = (float*)(smem + 69632);                  // [4][128] f32
  float* qvp = (float*)(smem + 71680);                  // [4][128] f32

  // ---- prologue extras: W_Q frags to regs, h_v to LDS (drain with rA0) ----
  short8v wq[4];
  #pragma unroll
  for (int ks = 0; ks < 4; ++ks)
    wq[ks] = *(const short8v*)(Wq2 + ((size_t)(ks*8 + wave)*64 + lane)*8);
  if (tid < 128) {
    int tok = tid >> 5, q = tid & 31;
    *(float4*)&hvp[tok*128 + q*4] = *(const float4*)&h_v[(size_t)(bn0 + tok)*TH + q*4];
  }

  const int rowa = tid >> 2, cga = tid & 3;
  const int rowc = (rowa > 119) ? 119 : rowa;
  const float* aptr = A + ((size_t)blockIdx.x*120 + rowc)*TNIN + cga*8;

  #define ISSUE_B(K)                                                             \
    { gload16(Wc2 + (size_t)(K)*8192 + tid*8,       &Bl[((K)%3)*8192 + tid*8]);  \
      gload16(Wc2 + (size_t)(K)*8192 + (tid+512)*8, &Bl[((K)%3)*8192 + (tid+512)*8]); }

  #define WRITE_A(K, S)                                                     \
    { short8v w;                                                            \
      w[0]=(short)f2bf(ra[S][0].x); w[1]=(short)f2bf(ra[S][0].y);           \
      w[2]=(short)f2bf(ra[S][0].z); w[3]=(short)f2bf(ra[S][0].w);           \
      w[4]=(short)f2bf(ra[S][1].x); w[5]=(short)f2bf(ra[S][1].y);           \
      w[6]=(short)f2bf(ra[S][1].z); w[7]=(short)f2bf(ra[S][1].w);           \
      *(short8v*)&Al[(((K)&1)*128 + rowa)*40 + cga*8] = w; }

  float4 ra[3][2];
  f32x4 acc[4][4] = {};

  // prologue: rA(0); B(0); B(1); rA(1); rA(2); write A(0)
  ra[0][0] = *(const float4*)(aptr + 0);
  ra[0][1] = *(const float4*)(aptr + 4);
  ISSUE_B(0);
  ISSUE_B(1);
  ra[1][0] = *(const float4*)(aptr + 32);
  ra[1][1] = *(const float4*)(aptr + 36);
  ra[2][0] = *(const float4*)(aptr + 64);
  ra[2][1] = *(const float4*)(aptr + 68);
  WRITE_A(0, 0);

  #pragma unroll
  for (int k = 0; k < 8; ++k) {
    if (k == 7)      asm volatile("s_waitcnt vmcnt(0)" ::: "memory");
    else if (k == 6) asm volatile("s_waitcnt vmcnt(4)" ::: "memory");
    else             asm volatile("s_waitcnt vmcnt(6)" ::: "memory");
    __builtin_amdgcn_s_barrier();

    if (k < 6) ISSUE_B(k+2);
    if (k < 5) {
      ra[k%3][0] = *(const float4*)(aptr + (k+3)*32);
      ra[k%3][1] = *(const float4*)(aptr + (k+3)*32 + 4);
    }

    short8v af[4];
    #pragma unroll
    for (int m = 0; m < 4; ++m)
      af[m] = *(const short8v*)&Al[((k&1)*128 + mh*64 + m*16 + lm)*40 + lgp*8];

    #pragma unroll
    for (int n = 0; n < 4; ++n) {
      short8v b = *(const short8v*)&Bl[(k%3)*8192 + ((nq*4 + n)*64 + lane)*8];
      #pragma unroll
      for (int m = 0; m < 4; ++m)
        acc[m][n] = __builtin_amdgcn_mfma_f32_16x16x32_bf16(b, af[m], acc[m][n], 0, 0, 0);
    }

    if (k < 7) WRITE_A(k+1, (k+1)%3);
  }
  #undef ISSUE_B
  #undef WRITE_A

  // ---- Q = h_v @ W_Q^T (MFMA, swapped mapping: D[row=lm][col=wave*16+lgp*4+r]) ----
  {
    f32x4 qacc = {};
    const int tokc = (lm < 4) ? lm : 3;
    #pragma unroll
    for (int ks = 0; ks < 4; ++ks) {
      const float* hp = hvp + tokc*128 + ks*32 + lgp*8;
      float4 lo = *(const float4*)hp;
      float4 hi = *(const float4*)(hp + 4);
      short8v ha;
      ha[0]=(short)f2bf(lo.x); ha[1]=(short)f2bf(lo.y);
      ha[2]=(short)f2bf(lo.z); ha[3]=(short)f2bf(lo.w);
      ha[4]=(short)f2bf(hi.x); ha[5]=(short)f2bf(hi.y);
      ha[6]=(short)f2bf(hi.z); ha[7]=(short)f2bf(hi.w);
      qacc = __builtin_amdgcn_mfma_f32_16x16x32_bf16(wq[ks], ha, qacc, 0, 0, 0);
    }
    if (lm < 4) *(f32x4*)&qvp[lm*128 + wave*16 + lgp*4] = qacc;
  }

  __syncthreads();   // all Bl/Al reads + qv writes done before KVs overlay

  #pragma unroll
  for (int m = 0; m < 4; ++m) {
    int row = mh*64 + m*16 + lm;
    #pragma unroll
    for (int n = 0; n < 4; ++n) {
      int col = nq*64 + n*16 + lgp*4;
      short4v p;
      p[0]=(short)f2bf(acc[m][n][0]); p[1]=(short)f2bf(acc[m][n][1]);
      p[2]=(short)f2bf(acc[m][n][2]); p[3]=(short)f2bf(acc[m][n][3]);
      *(short4v*)&KVs[row*ROWP + col] = p;
    }
  }
  __syncthreads();

  // ---- logits + masked softmax (Q from LDS f32) ----
  {
    int tok = tid >> 7, h = (tid >> 5) & 3, k = tid & 31;
    int gtok = bn0 + tok;
    float s = 0.f;
    float ma = 0.f;
    if (k < TK) {
      const float* qp = &qvp[tok*128 + h*32];
      const unsigned short* kp = &KVs[(tok*TK + k)*ROWP + h*32];
      #pragma unroll
      for (int j = 0; j < 4; ++j) {
        short8v kf = *(const short8v*)(kp + j*8);
        float4 qa = *(const float4*)(qp + j*8);
        float4 qb = *(const float4*)(qp + j*8 + 4);
        s += qa.x*bf2f((unsigned short)kf[0]) + qa.y*bf2f((unsigned short)kf[1])
           + qa.z*bf2f((unsigned short)kf[2]) + qa.w*bf2f((unsigned short)kf[3])
           + qb.x*bf2f((unsigned short)kf[4]) + qb.y*bf2f((unsigned short)kf[5])
           + qb.z*bf2f((unsigned short)kf[6]) + qb.w*bf2f((unsigned short)kf[7]);
      }
      ma = mask_attend[(size_t)gtok*TK + k];
    }
    bool ok = (k < TK) && (ma > 0.f);
    float val = ok ? s * INV_SQRT_D : NEG_INF;
    float mm = val;
    #pragma unroll
    for (int d = 16; d >= 1; d >>= 1) mm = fmaxf(mm, __shfl_xor(mm, d, 32));
    float e = ok ? expf(val - mm) : 0.f;
    float ss = e;
    #pragma unroll
    for (int d = 16; d >= 1; d >>= 1) ss += __shfl_xor(ss, d, 32);
    att[(tok*4 + h)*32 + k] = e / ss;
  }
  __syncthreads();

  // ---- PV ----
  {
    int tok = tid >> 7, c = tid & 127;
    int gtok = bn0 + tok;
    const float* ar = &att[(tok*4 + (c >> 5))*32];
    const unsigned short* vb = &KVs[tok*TK*ROWP + TH + c];
    float u = 0.f;
    #pragma unroll
    for (int k = 0; k < TK; ++k)
      u += ar[k] * bf2f(vb[k*ROWP]);
    ul[(size_t)gtok*TH + c] = u;
  }
}

// ---------------------------------------------------------------------------
// K2: ffn_all = W_O-proj + LN0 + FFN(GEMM1,GEMM2) + LN1 + mask, all MFMA bf16.
// grid = 250 x 256 thr (4 waves), 32 tokens/block, all blocks CU-concurrent.
// Lane layout for every GEMM: D[row = m*16+lm][col = (wave*NW+n)*16+lgp*4+r].
// LN0 output (Hn) kept in regs for LN1 residual (identical lane layout).
// ---------------------------------------------------------------------------
__global__ __launch_bounds__(256, 4) void ffn_all_kernel(
    const float* __restrict__ ul, const unsigned short* __restrict__ Wp2,
    const float* __restrict__ h_v,
    const float* __restrict__ gain0, const float* __restrict__ bias0,
    const unsigned short* __restrict__ Wi2, const unsigned short* __restrict__ Wo2,
    const float* __restrict__ b_in, const float* __restrict__ b_out,
    const float* __restrict__ gain1, const float* __restrict__ bias1,
    const float* __restrict__ mask_v, float* __restrict__ out)
{
  const int tid  = threadIdx.x;
  const int tok0 = blockIdx.x * 32;
  const int wave = tid >> 6;
  const int lane = tid & 63;
  const int lm   = lane & 15;
  const int lgp  = lane >> 4;

  __shared__ __align__(16) char smem[78336];
  unsigned short* Bst = (unsigned short*)smem;            // 32 KB stage arena
  unsigned short* At  = (unsigned short*)(smem + 32768);  // [32][136] bf16
  unsigned short* Zs  = (unsigned short*)(smem + 41472);  // [32][520] bf16
  float* bin  = (float*)(smem + 74752);                   // [512]
  float* part = (float*)(smem + 76800);                   // [32][4][2]
  float* red  = (float*)(smem + 77824);                   // [32][2]

  // ---- stage: At <- bf16(ul), bin <- b_in, Bst <- Wp2 (32 KB whole) ----
  for (int t = tid; t < 1024; t += 256) {
    int row = t >> 5, q = t & 31;
    float4 v = *(const float4*)&ul[(size_t)(tok0+row)*TH + q*4];
    short4v w;
    w[0]=(short)f2bf(v.x); w[1]=(short)f2bf(v.y);
    w[2]=(short)f2bf(v.z); w[3]=(short)f2bf(v.w);
    *(short4v*)&At[row*136 + q*4] = w;
  }
  if (tid < 128) *(float4*)&bin[tid*4] = *(const float4*)&b_in[tid*4];
  #pragma unroll
  for (int p = 0; p < 8; ++p)
    gload16(Wp2 + (size_t)(tid + p*256)*8, &Bst[(tid + p*256)*8]);
  asm volatile("s_waitcnt vmcnt(0)" ::: "memory");
  __syncthreads();

  // ---- GEMM-O: dh = ul @ W_O^T  (N=128: wave owns n-frags wave*2..+1) ----
  f32x4 acco[2][2] = {};
  #pragma unroll
  for (int ks = 0; ks < 4; ++ks) {
    short8v a0 = *(const short8v*)&At[lm*136      + ks*32 + lgp*8];
    short8v a1 = *(const short8v*)&At[(16+lm)*136 + ks*32 + lgp*8];
    #pragma unroll
    for (int n = 0; n < 2; ++n) {
      short8v b = *(const short8v*)&Bst[((size_t)(ks*8 + wave*2 + n)*64 + lane)*8];
      acco[0][n] = __builtin_amdgcn_mfma_f32_16x16x32_bf16(b, a0, acco[0][n], 0, 0, 0);
      acco[1][n] = __builtin_amdgcn_mfma_f32_16x16x32_bf16(b, a1, acco[1][n], 0, 0, 0);
    }
  }

  // ---- x = dh + h_v ; LN0 (cross-wave reduce); Hn -> regs + At(bf16) ----
  f32x4 hn[2][2];
  {
    f32x4 x[2][2];
    float s1r[2] = {0.f, 0.f}, s2r[2] = {0.f, 0.f};
    #pragma unroll
    for (int m = 0; m < 2; ++m) {
      int row = m*16 + lm;
      #pragma unroll
      for (int n = 0; n < 2; ++n) {
        int col = (wave*2 + n)*16 + lgp*4;
        float4 hv = *(const float4*)&h_v[(size_t)(tok0+row)*TH + col];
        x[m][n][0] = acco[m][n][0] + hv.x;
        x[m][n][1] = acco[m][n][1] + hv.y;
        x[m][n][2] = acco[m][n][2] + hv.z;
        x[m][n][3] = acco[m][n][3] + hv.w;
        #pragma unroll
        for (int r = 0; r < 4; ++r) {
          s1r[m] += x[m][n][r];
          s2r[m] += x[m][n][r]*x[m][n][r];
        }
      }
    }
    #pragma unroll
    for (int m = 0; m < 2; ++m) {
      s1r[m] += __shfl_xor(s1r[m], 16); s2r[m] += __shfl_xor(s2r[m], 16);
      s1r[m] += __shfl_xor(s1r[m], 32); s2r[m] += __shfl_xor(s2r[m], 32);
    }
    if (lgp == 0) {
      part[(lm*4      + wave)*2 + 0] = s1r[0];
      part[(lm*4      + wave)*2 + 1] = s2r[0];
      part[((16+lm)*4 + wave)*2 + 0] = s1r[1];
      part[((16+lm)*4 + wave)*2 + 1] = s2r[1];
    }
    __syncthreads();
    if (tid < 32) {
      float s1 = 0.f, s2 = 0.f;
      #pragma unroll
      for (int w = 0; w < 4; ++w) { s1 += part[(tid*4+w)*2]; s2 += part[(tid*4+w)*2+1]; }
      float mu  = s1*(1.f/128.f);
      float var = (s2 - 128.f*mu*mu)*(1.f/127.f);
      red[tid*2]   = mu;
      red[tid*2+1] = 1.f/(sqrtf(var+LN_EPS)+LN_EPS);
    }
    __syncthreads();
    #pragma unroll
    for (int m = 0; m < 2; ++m) {
      int row = m*16 + lm;
      float mu = red[row*2], inv = red[row*2+1];
      #pragma unroll
      for (int n = 0; n < 2; ++n) {
        int col = (wave*2 + n)*16 + lgp*4;
        float4 g = *(const float4*)&gain0[col];
        float4 b = *(const float4*)&bias0[col];
        hn[m][n][0] = g.x*(x[m][n][0]-mu)*inv + b.x;
        hn[m][n][1] = g.y*(x[m][n][1]-mu)*inv + b.y;
        hn[m][n][2] = g.z*(x[m][n][2]-mu)*inv + b.z;
        hn[m][n][3] = g.w*(x[m][n][3]-mu)*inv + b.w;
        short4v p;
        p[0]=(short)f2bf(hn[m][n][0]); p[1]=(short)f2bf(hn[m][n][1]);
        p[2]=(short)f2bf(hn[m][n][2]); p[3]=(short)f2bf(hn[m][n][3]);
        *(short4v*)&At[row*136 + col] = p;   // At reads done (GEMM-O over)
      }
    }
  }
  __syncthreads();

  // ---- GEMM1: Z = relu(Hn @ W_in^T + b_in)  (N=512: wave owns 8 n-frags) ----
  f32x4 acc1[2][8] = {};
  #pragma unroll
  for (int ks = 0; ks < 4; ++ks) {
    #pragma unroll
    for (int p = 0; p < 8; ++p)
      gload16(Wi2 + (size_t)ks*16384 + (tid + p*256)*8, &Bst[(tid + p*256)*8]);
    asm volatile("s_waitcnt vmcnt(0)" ::: "memory");
    __syncthreads();

    short8v a0 = *(const short8v*)&At[lm*136      + ks*32 + lgp*8];
    short8v a1 = *(const short8v*)&At[(16+lm)*136 + ks*32 + lgp*8];
    #pragma unroll
    for (int n = 0; n < 8; ++n) {
      short8v b = *(const short8v*)&Bst[((wave*8 + n)*64 + lane)*8];
      acc1[0][n] = __builtin_amdgcn_mfma_f32_16x16x32_bf16(b, a0, acc1[0][n], 0, 0, 0);
      acc1[1][n] = __builtin_amdgcn_mfma_f32_16x16x32_bf16(b, a1, acc1[1][n], 0, 0, 0);
    }
    __syncthreads();
  }

  #pragma unroll
  for (int m = 0; m < 2; ++m) {
    int row = m*16 + lm;
    #pragma unroll
    for (int n = 0; n < 8; ++n) {
      int col = (wave*8 + n)*16 + lgp*4;
      float4 bv = *(const float4*)&bin[col];
      short4v p;
      p[0]=(short)f2bf(fmaxf(acc1[m][n][0] + bv.x, 0.f));
      p[1]=(short)f2bf(fmaxf(acc1[m][n][1] + bv.y, 0.f));
      p[2]=(short)f2bf(fmaxf(acc1[m][n][2] + bv.z, 0.f));
      p[3]=(short)f2bf(fmaxf(acc1[m][n][3] + bv.w, 0.f));
      *(short4v*)&Zs[row*520 + col] = p;
    }
  }
  __syncthreads();

  // ---- GEMM2: Y = Z @ W_out^T (K=512, 8 stages x 2 ks) ----
  f32x4 acc2[2][2] = {};
  #pragma unroll
  for (int ks2 = 0; ks2 < 8; ++ks2) {
    #pragma unroll
    for (int p = 0; p < 4; ++p)
      gload16(Wo2 + (size_t)ks2*8192 + (tid + p*256)*8, &Bst[(tid + p*256)*8]);
    asm volatile("s_waitcnt vmcnt(0)" ::: "memory");
    __syncthreads();

    #pragma unroll
    for (int s = 0; s < 2; ++s) {
      int ks = ks2*2 + s;
      short8v a0 = *(const short8v*)&Zs[lm*520      + ks*32 + lgp*8];
      short8v a1 = *(const short8v*)&Zs[(16+lm)*520 + ks*32 + lgp*8];
      #pragma unroll
      for (int n = 0; n < 2; ++n) {
        short8v b = *(const short8v*)&Bst[(s*4096) + ((wave*2 + n)*64 + lane)*8];
        acc2[0][n] = __builtin_amdgcn_mfma_f32_16x16x32_bf16(b, a0, acc2[0][n], 0, 0, 0);
        acc2[1][n] = __builtin_amdgcn_mfma_f32_16x16x32_bf16(b, a1, acc2[1][n], 0, 0, 0);
      }
    }
    __syncthreads();
  }

  // ---- x2 = Y + b_out + Hn(regs); LN1; mask; store ----
  {
    f32x4 x[2][2];
    float s1r[2] = {0.f, 0.f}, s2r[2] = {0.f, 0.f};
    #pragma unroll
    for (int m = 0; m < 2; ++m) {
      #pragma unroll
      for (int n = 0; n < 2; ++n) {
        int col = (wave*2 + n)*16 + lgp*4;
        float4 bo = *(const float4*)&b_out[col];
        x[m][n][0] = acc2[m][n][0] + bo.x + hn[m][n][0];
        x[m][n][1] = acc2[m][n][1] + bo.y + hn[m][n][1];
        x[m][n][2] = acc2[m][n][2] + bo.z + hn[m][n][2];
        x[m][n][3] = acc2[m][n][3] + bo.w + hn[m][n][3];
        #pragma unroll
        for (int r = 0; r < 4; ++r) {
          s1r[m] += x[m][n][r];
          s2r[m] += x[m][n][r]*x[m][n][r];
        }
      }
    }
    #pragma unroll
    for (int m = 0; m < 2; ++m) {
      s1r[m] += __shfl_xor(s1r[m], 16); s2r[m] += __shfl_xor(s2r[m], 16);
      s1r[m] += __shfl_xor(s1r[m], 32); s2r[m] += __shfl_xor(s2r[m], 32);
    }
    if (lgp == 0) {
      part[(lm*4      + wave)*2 + 0] = s1r[0];
      part[(lm*4      + wave)*2 + 1] = s2r[0];
      part[((16+lm)*4 + wave)*2 + 0] = s1r[1];
      part[((16+lm)*4 + wave)*2 + 1] = s2r[1];
    }
    __syncthreads();
    if (tid < 32) {
      float s1 = 0.f, s2 = 0.f;
      #pragma unroll
      for (int w = 0; w < 4; ++w) { s1 += part[(tid*4+w)*2]; s2 += part[(tid*4+w)*2+1]; }
      float mu  = s1*(1.f/128.f);
      float var = (s2 - 128.f*mu*mu)*(1.f/127.f);
      red[tid*2]   = mu;
      red[tid*2+1] = 1.f/(sqrtf(var+LN_EPS)+LN_EPS);
    }
    __syncthreads();
    #pragma unroll
    for (int m = 0; m < 2; ++m) {
      int row = m*16 + lm;
      float mu = red[row*2], inv = red[row*2+1];
      float mv = mask_v[tok0 + row];
      #pragma unroll
      for (int n = 0; n < 2; ++n) {
        int col = (wave*2 + n)*16 + lgp*4;
        float4 g = *(const float4*)&gain1[col];
        float4 b = *(const float4*)&bias1[col];
        float4 y;
        y.x = mv*(g.x*(x[m][n][0]-mu)*inv + b.x);
        y.y = mv*(g.y*(x[m][n][1]-mu)*inv + b.y);
        y.z = mv*(g.z*(x[m][n][2]-mu)*inv + b.z);
        y.w = mv*(g.w*(x[m][n][3]-mu)*inv + b.w);
        *(float4*)&out[(size_t)(tok0+row)*TH + col] = y;
      }
    }
  }
}

// ---------------------------------------------------------------------------
extern "C" void kernel_launch(void* const* d_in, const int* in_sizes, int n_in,
                              void* d_out, int out_size, void* d_ws, size_t ws_size,
                              hipStream_t stream)
{
  const float* h_v         = (const float*)d_in[0];
  const float* h_e         = (const float*)d_in[1];
  const float* mask_v      = (const float*)d_in[2];
  const float* mask_attend = (const float*)d_in[3];
  const float* W_Q   = (const float*)d_in[4];
  const float* W_K   = (const float*)d_in[5];
  const float* W_V   = (const float*)d_in[6];
  const float* W_O   = (const float*)d_in[7];
  const float* gain0 = (const float*)d_in[8];
  const float* bias0 = (const float*)d_in[9];
  const float* gain1 = (const float*)d_in[10];
  const float* bias1 = (const float*)d_in[11];
  const float* W_in  = (const float*)d_in[12];
  const float* b_in  = (const float*)d_in[13];
  const float* W_out = (const float*)d_in[14];
  const float* b_out = (const float*)d_in[15];

  float* out = (float*)d_out;
  char* ws = (char*)d_ws;
  unsigned short* Wc2 = (unsigned short*)ws;               //  131,072 B
  unsigned short* Wq2 = (unsigned short*)(ws + 131072);    //   32,768 B
  unsigned short* Wp2 = (unsigned short*)(ws + 163840);    //   32,768 B
  unsigned short* Wi2 = (unsigned short*)(ws + 196608);    //  131,072 B
  unsigned short* Wo2 = (unsigned short*)(ws + 327680);    //  131,072 B
  float* ul = (float*)(ws + 458752);                       // 4,096,000 B

  conv_weights_kernel<<<896, 256, 0, stream>>>(W_K, W_V, W_Q, W_O, W_in, W_out,
                                               Wc2, Wq2, Wp2, Wi2, Wo2);
  kvattn_kernel<<<NTOK/4, 512, 0, stream>>>(h_e, Wc2, Wq2, h_v, mask_attend, ul);
  ffn_all_kernel<<<NTOK/32, 256, 0, stream>>>(ul, Wp2, h_v, gain0, bias0,
                                              Wi2, Wo2, b_in, b_out,
                                              gain1, bias1, mask_v, out);
}

// Round 10
// 80.920 us; speedup vs baseline: 1.2900x; 1.2900x over previous
//
#include <hip/hip_runtime.h>
#include <math.h>

#define TK 30
#define TH 128
#define TNIN 256
#define TDFF 512
#define NTOK 8000
#define ROWP 264   // KVs row stride in u16

typedef __attribute__((ext_vector_type(8))) short short8v;
typedef __attribute__((ext_vector_type(4))) short short4v;
typedef __attribute__((ext_vector_type(4))) float f32x4;

constexpr float LN_EPS = 1e-6f;
constexpr float NEG_INF = -3.402823466e38f;
constexpr float INV_SQRT_D = 0.17677669529663687f;  // 1/sqrt(32)

static __device__ __forceinline__ unsigned short f2bf(float f) {
  unsigned u = __float_as_uint(f);
  u = u + 0x7fffu + ((u >> 16) & 1u);
  return (unsigned short)(u >> 16);
}
static __device__ __forceinline__ float bf2f(unsigned short s) {
  return __uint_as_float(((unsigned)s) << 16);
}
static __device__ __forceinline__ void gload16(const void* gsrc, void* ldst) {
  __builtin_amdgcn_global_load_lds(
      (const __attribute__((address_space(1))) unsigned int*)gsrc,
      (__attribute__((address_space(3))) unsigned int*)ldst, 16, 0, 0);
}

// ---------------------------------------------------------------------------
// K0: weight prep (verbatim R9, verified). Frag-linear bf16:
//   elem ((ks*NF + n)*64 + lane)*8 + j = W[n*16+(lane&15)][ks*32+(lane>>4)*8+j]
// ---------------------------------------------------------------------------
__global__ void conv_weights_kernel(const float* __restrict__ W_K,
                                    const float* __restrict__ W_V,
                                    const float* __restrict__ W_Q,
                                    const float* __restrict__ W_O,
                                    const float* __restrict__ W_in,
                                    const float* __restrict__ W_out,
                                    unsigned short* __restrict__ Wc2,
                                    unsigned short* __restrict__ Wq2,
                                    unsigned short* __restrict__ Wp2,
                                    unsigned short* __restrict__ Wi2,
                                    unsigned short* __restrict__ Wo2)
{
  int idx = blockIdx.x * 256 + threadIdx.x;   // 0..229375
  if (idx < 65536) {
    int e = idx >> 3, j = idx & 7;
    int kk = e >> 10, n = (e >> 6) & 15, lane = e & 63;
    int r = n*16 + (lane & 15);
    int c = kk*32 + (lane >> 4)*8 + j;
    float v = (r < TH) ? W_K[(size_t)r*TNIN + c] : W_V[(size_t)(r-TH)*TNIN + c];
    Wc2[idx] = f2bf(v);
  } else if (idx < 81920) {
    int i2 = idx - 65536;
    int e = i2 >> 3, j = i2 & 7;
    int kk = e >> 9, n = (e >> 6) & 7, lane = e & 63;
    int r = n*16 + (lane & 15);
    int c = kk*32 + (lane >> 4)*8 + j;
    Wq2[i2] = f2bf(W_Q[(size_t)r*TH + c]);
  } else if (idx < 98304) {
    int ip = idx - 81920;
    int e = ip >> 3, j = ip & 7;
    int kk = e >> 9, n = (e >> 6) & 7, lane = e & 63;
    int r = n*16 + (lane & 15);
    int c = kk*32 + (lane >> 4)*8 + j;
    Wp2[ip] = f2bf(W_O[(size_t)r*TH + c]);
  } else if (idx < 163840) {
    int i3 = idx - 98304;
    int e = i3 >> 3, j = i3 & 7;
    int ks = e >> 11, n = (e >> 6) & 31, lane = e & 63;
    int r = n*16 + (lane & 15);
    int c = ks*32 + (lane >> 4)*8 + j;
    Wi2[i3] = f2bf(W_in[(size_t)r*TH + c]);
  } else {
    int i4 = idx - 163840;
    int e = i4 >> 3, j = i4 & 7;
    int ks = e >> 9, n = (e >> 6) & 7, lane = e & 63;
    int r = n*16 + (lane & 15);
    int c = ks*32 + (lane >> 4)*8 + j;
    Wo2[i4] = f2bf(W_out[(size_t)r*TDFF + c]);
  }
}

// ---------------------------------------------------------------------------
// K1: fused Q-proj + KV-GEMM + attention core.
// R10: Q-MFMA moved AFTER the C-writeout (acc dead -> no extra register
// pressure in the GEMM loop; wq fragments loaded from L2 at that point).
// GEMM loop register set identical to R8's audited version.
// ---------------------------------------------------------------------------
__global__ __launch_bounds__(512, 4) void kvattn_kernel(
    const float* __restrict__ A, const unsigned short* __restrict__ Wc2,
    const unsigned short* __restrict__ Wq2, const float* __restrict__ h_v,
    const float* __restrict__ mask_attend, float* __restrict__ ul)
{
  const int tid  = threadIdx.x;
  const int wave = tid >> 6;
  const int lane = tid & 63;
  const int lm   = lane & 15;
  const int lgp  = lane >> 4;
  const int mh   = wave >> 2;   // 0..1
  const int nq   = wave & 3;    // 0..3
  const int bn0  = blockIdx.x * 4;

  __shared__ __align__(16) char smem[73728];
  unsigned short* Bl  = (unsigned short*)smem;          // [3][8192]   0..49152
  unsigned short* Al  = (unsigned short*)(smem + 49152);// [2][128][40] ..69632
  unsigned short* KVs = (unsigned short*)smem;          // [128][264] overlay 0..67584
  float* att = (float*)(smem + 67584);                  // [4][4][32] (Al tail, dead)
  float* hvp = (float*)(smem + 69632);                  // [4][128] f32
  float* qvp = (float*)(smem + 71680);                  // [4][128] f32

  // ---- prologue extras: h_v to LDS (visible after first loop barrier) ----
  if (tid < 128) {
    int tok = tid >> 5, q = tid & 31;
    *(float4*)&hvp[tok*128 + q*4] = *(const float4*)&h_v[(size_t)(bn0 + tok)*TH + q*4];
  }

  const int rowa = tid >> 2, cga = tid & 3;
  const int rowc = (rowa > 119) ? 119 : rowa;
  const float* aptr = A + ((size_t)blockIdx.x*120 + rowc)*TNIN + cga*8;

  #define ISSUE_B(K)                                                             \
    { gload16(Wc2 + (size_t)(K)*8192 + tid*8,       &Bl[((K)%3)*8192 + tid*8]);  \
      gload16(Wc2 + (size_t)(K)*8192 + (tid+512)*8, &Bl[((K)%3)*8192 + (tid+512)*8]); }

  #define WRITE_A(K, S)                                                     \
    { short8v w;                                                            \
      w[0]=(short)f2bf(ra[S][0].x); w[1]=(short)f2bf(ra[S][0].y);           \
      w[2]=(short)f2bf(ra[S][0].z); w[3]=(short)f2bf(ra[S][0].w);           \
      w[4]=(short)f2bf(ra[S][1].x); w[5]=(short)f2bf(ra[S][1].y);           \
      w[6]=(short)f2bf(ra[S][1].z); w[7]=(short)f2bf(ra[S][1].w);           \
      *(short8v*)&Al[(((K)&1)*128 + rowa)*40 + cga*8] = w; }

  float4 ra[3][2];
  f32x4 acc[4][4] = {};

  // prologue: rA(0); B(0); B(1); rA(1); rA(2); write A(0)
  ra[0][0] = *(const float4*)(aptr + 0);
  ra[0][1] = *(const float4*)(aptr + 4);
  ISSUE_B(0);
  ISSUE_B(1);
  ra[1][0] = *(const float4*)(aptr + 32);
  ra[1][1] = *(const float4*)(aptr + 36);
  ra[2][0] = *(const float4*)(aptr + 64);
  ra[2][1] = *(const float4*)(aptr + 68);
  WRITE_A(0, 0);

  #pragma unroll
  for (int k = 0; k < 8; ++k) {
    if (k == 7)      asm volatile("s_waitcnt vmcnt(0)" ::: "memory");
    else if (k == 6) asm volatile("s_waitcnt vmcnt(4)" ::: "memory");
    else             asm volatile("s_waitcnt vmcnt(6)" ::: "memory");
    __builtin_amdgcn_s_barrier();

    if (k < 6) ISSUE_B(k+2);
    if (k < 5) {
      ra[k%3][0] = *(const float4*)(aptr + (k+3)*32);
      ra[k%3][1] = *(const float4*)(aptr + (k+3)*32 + 4);
    }

    short8v af[4];
    #pragma unroll
    for (int m = 0; m < 4; ++m)
      af[m] = *(const short8v*)&Al[((k&1)*128 + mh*64 + m*16 + lm)*40 + lgp*8];

    #pragma unroll
    for (int n = 0; n < 4; ++n) {
      short8v b = *(const short8v*)&Bl[(k%3)*8192 + ((nq*4 + n)*64 + lane)*8];
      #pragma unroll
      for (int m = 0; m < 4; ++m)
        acc[m][n] = __builtin_amdgcn_mfma_f32_16x16x32_bf16(b, af[m], acc[m][n], 0, 0, 0);
    }

    if (k < 7) WRITE_A(k+1, (k+1)%3);
  }
  #undef ISSUE_B
  #undef WRITE_A

  __syncthreads();   // all Bl/Al reads done before KVs overlay

  // ---- C writeout (verified swapped-operand mapping) ----
  #pragma unroll
  for (int m = 0; m < 4; ++m) {
    int row = mh*64 + m*16 + lm;
    #pragma unroll
    for (int n = 0; n < 4; ++n) {
      int col = nq*64 + n*16 + lgp*4;
      short4v p;
      p[0]=(short)f2bf(acc[m][n][0]); p[1]=(short)f2bf(acc[m][n][1]);
      p[2]=(short)f2bf(acc[m][n][2]); p[3]=(short)f2bf(acc[m][n][3]);
      *(short4v*)&KVs[row*ROWP + col] = p;
    }
  }

  // ---- Q = h_v @ W_Q^T (R10: acc now dead; wq loaded here from L2) ----
  // D[row=lm (token, lm<4 valid)][col = wave*16 + lgp*4 + r]
  {
    f32x4 qacc = {};
    const int tokc = (lm < 4) ? lm : 3;
    #pragma unroll
    for (int ks = 0; ks < 4; ++ks) {
      short8v wq = *(const short8v*)(Wq2 + ((size_t)(ks*8 + wave)*64 + lane)*8);
      const float* hp = hvp + tokc*128 + ks*32 + lgp*8;
      float4 lo = *(const float4*)hp;
      float4 hi = *(const float4*)(hp + 4);
      short8v ha;
      ha[0]=(short)f2bf(lo.x); ha[1]=(short)f2bf(lo.y);
      ha[2]=(short)f2bf(lo.z); ha[3]=(short)f2bf(lo.w);
      ha[4]=(short)f2bf(hi.x); ha[5]=(short)f2bf(hi.y);
      ha[6]=(short)f2bf(hi.z); ha[7]=(short)f2bf(hi.w);
      qacc = __builtin_amdgcn_mfma_f32_16x16x32_bf16(wq, ha, qacc, 0, 0, 0);
    }
    if (lm < 4) *(f32x4*)&qvp[lm*128 + wave*16 + lgp*4] = qacc;
  }
  __syncthreads();   // KVs + qvp visible

  // ---- logits + masked softmax (Q from LDS f32) ----
  {
    int tok = tid >> 7, h = (tid >> 5) & 3, k = tid & 31;
    int gtok = bn0 + tok;
    float s = 0.f;
    float ma = 0.f;
    if (k < TK) {
      const float* qp = &qvp[tok*128 + h*32];
      const unsigned short* kp = &KVs[(tok*TK + k)*ROWP + h*32];
      #pragma unroll
      for (int j = 0; j < 4; ++j) {
        short8v kf = *(const short8v*)(kp + j*8);
        float4 qa = *(const float4*)(qp + j*8);
        float4 qb = *(const float4*)(qp + j*8 + 4);
        s += qa.x*bf2f((unsigned short)kf[0]) + qa.y*bf2f((unsigned short)kf[1])
           + qa.z*bf2f((unsigned short)kf[2]) + qa.w*bf2f((unsigned short)kf[3])
           + qb.x*bf2f((unsigned short)kf[4]) + qb.y*bf2f((unsigned short)kf[5])
           + qb.z*bf2f((unsigned short)kf[6]) + qb.w*bf2f((unsigned short)kf[7]);
      }
      ma = mask_attend[(size_t)gtok*TK + k];
    }
    bool ok = (k < TK) && (ma > 0.f);
    float val = ok ? s * INV_SQRT_D : NEG_INF;
    float mm = val;
    #pragma unroll
    for (int d = 16; d >= 1; d >>= 1) mm = fmaxf(mm, __shfl_xor(mm, d, 32));
    float e = ok ? expf(val - mm) : 0.f;
    float ss = e;
    #pragma unroll
    for (int d = 16; d >= 1; d >>= 1) ss += __shfl_xor(ss, d, 32);
    att[(tok*4 + h)*32 + k] = e / ss;
  }
  __syncthreads();

  // ---- PV ----
  {
    int tok = tid >> 7, c = tid & 127;
    int gtok = bn0 + tok;
    const float* ar = &att[(tok*4 + (c >> 5))*32];
    const unsigned short* vb = &KVs[tok*TK*ROWP + TH + c];
    float u = 0.f;
    #pragma unroll
    for (int k = 0; k < TK; ++k)
      u += ar[k] * bf2f(vb[k*ROWP]);
    ul[(size_t)gtok*TH + c] = u;
  }
}

// ---------------------------------------------------------------------------
// K2: ffn_all = W_O-proj + LN0 + FFN + LN1 + mask (all MFMA bf16).
// R10: plain __launch_bounds__(256) -- no min-waves arg, no VGPR cap (the
// R9 ",4" capped VGPR at 128 and spilled the 100+ live accumulator regs).
// ---------------------------------------------------------------------------
__global__ __launch_bounds__(256) void ffn_all_kernel(
    const float* __restrict__ ul, const unsigned short* __restrict__ Wp2,
    const float* __restrict__ h_v,
    const float* __restrict__ gain0, const float* __restrict__ bias0,
    const unsigned short* __restrict__ Wi2, const unsigned short* __restrict__ Wo2,
    const float* __restrict__ b_in, const float* __restrict__ b_out,
    const float* __restrict__ gain1, const float* __restrict__ bias1,
    const float* __restrict__ mask_v, float* __restrict__ out)
{
  const int tid  = threadIdx.x;
  const int tok0 = blockIdx.x * 32;
  const int wave = tid >> 6;
  const int lane = tid & 63;
  const int lm   = lane & 15;
  const int lgp  = lane >> 4;

  __shared__ __align__(16) char smem[78336];
  unsigned short* Bst = (unsigned short*)smem;            // 32 KB stage arena
  unsigned short* At  = (unsigned short*)(smem + 32768);  // [32][136] bf16
  unsigned short* Zs  = (unsigned short*)(smem + 41472);  // [32][520] bf16
  float* bin  = (float*)(smem + 74752);                   // [512]
  float* part = (float*)(smem + 76800);                   // [32][4][2]
  float* red  = (float*)(smem + 77824);                   // [32][2]

  // ---- stage: At <- bf16(ul), bin <- b_in, Bst <- Wp2 (32 KB whole) ----
  for (int t = tid; t < 1024; t += 256) {
    int row = t >> 5, q = t & 31;
    float4 v = *(const float4*)&ul[(size_t)(tok0+row)*TH + q*4];
    short4v w;
    w[0]=(short)f2bf(v.x); w[1]=(short)f2bf(v.y);
    w[2]=(short)f2bf(v.z); w[3]=(short)f2bf(v.w);
    *(short4v*)&At[row*136 + q*4] = w;
  }
  if (tid < 128) *(float4*)&bin[tid*4] = *(const float4*)&b_in[tid*4];
  #pragma unroll
  for (int p = 0; p < 8; ++p)
    gload16(Wp2 + (size_t)(tid + p*256)*8, &Bst[(tid + p*256)*8]);
  asm volatile("s_waitcnt vmcnt(0)" ::: "memory");
  __syncthreads();

  // ---- GEMM-O: dh = ul @ W_O^T ----
  f32x4 acco[2][2] = {};
  #pragma unroll
  for (int ks = 0; ks < 4; ++ks) {
    short8v a0 = *(const short8v*)&At[lm*136      + ks*32 + lgp*8];
    short8v a1 = *(const short8v*)&At[(16+lm)*136 + ks*32 + lgp*8];
    #pragma unroll
    for (int n = 0; n < 2; ++n) {
      short8v b = *(const short8v*)&Bst[((size_t)(ks*8 + wave*2 + n)*64 + lane)*8];
      acco[0][n] = __builtin_amdgcn_mfma_f32_16x16x32_bf16(b, a0, acco[0][n], 0, 0, 0);
      acco[1][n] = __builtin_amdgcn_mfma_f32_16x16x32_bf16(b, a1, acco[1][n], 0, 0, 0);
    }
  }

  // ---- x = dh + h_v ; LN0 (cross-wave reduce); Hn -> regs + At(bf16) ----
  f32x4 hn[2][2];
  {
    f32x4 x[2][2];
    float s1r[2] = {0.f, 0.f}, s2r[2] = {0.f, 0.f};
    #pragma unroll
    for (int m = 0; m < 2; ++m) {
      int row = m*16 + lm;
      #pragma unroll
      for (int n = 0; n < 2; ++n) {
        int col = (wave*2 + n)*16 + lgp*4;
        float4 hv = *(const float4*)&h_v[(size_t)(tok0+row)*TH + col];
        x[m][n][0] = acco[m][n][0] + hv.x;
        x[m][n][1] = acco[m][n][1] + hv.y;
        x[m][n][2] = acco[m][n][2] + hv.z;
        x[m][n][3] = acco[m][n][3] + hv.w;
        #pragma unroll
        for (int r = 0; r < 4; ++r) {
          s1r[m] += x[m][n][r];
          s2r[m] += x[m][n][r]*x[m][n][r];
        }
      }
    }
    #pragma unroll
    for (int m = 0; m < 2; ++m) {
      s1r[m] += __shfl_xor(s1r[m], 16); s2r[m] += __shfl_xor(s2r[m], 16);
      s1r[m] += __shfl_xor(s1r[m], 32); s2r[m] += __shfl_xor(s2r[m], 32);
    }
    if (lgp == 0) {
      part[(lm*4      + wave)*2 + 0] = s1r[0];
      part[(lm*4      + wave)*2 + 1] = s2r[0];
      part[((16+lm)*4 + wave)*2 + 0] = s1r[1];
      part[((16+lm)*4 + wave)*2 + 1] = s2r[1];
    }
    __syncthreads();
    if (tid < 32) {
      float s1 = 0.f, s2 = 0.f;
      #pragma unroll
      for (int w = 0; w < 4; ++w) { s1 += part[(tid*4+w)*2]; s2 += part[(tid*4+w)*2+1]; }
      float mu  = s1*(1.f/128.f);
      float var = (s2 - 128.f*mu*mu)*(1.f/127.f);
      red[tid*2]   = mu;
      red[tid*2+1] = 1.f/(sqrtf(var+LN_EPS)+LN_EPS);
    }
    __syncthreads();
    #pragma unroll
    for (int m = 0; m < 2; ++m) {
      int row = m*16 + lm;
      float mu = red[row*2], inv = red[row*2+1];
      #pragma unroll
      for (int n = 0; n < 2; ++n) {
        int col = (wave*2 + n)*16 + lgp*4;
        float4 g = *(const float4*)&gain0[col];
        float4 b = *(const float4*)&bias0[col];
        hn[m][n][0] = g.x*(x[m][n][0]-mu)*inv + b.x;
        hn[m][n][1] = g.y*(x[m][n][1]-mu)*inv + b.y;
        hn[m][n][2] = g.z*(x[m][n][2]-mu)*inv + b.z;
        hn[m][n][3] = g.w*(x[m][n][3]-mu)*inv + b.w;
        short4v p;
        p[0]=(short)f2bf(hn[m][n][0]); p[1]=(short)f2bf(hn[m][n][1]);
        p[2]=(short)f2bf(hn[m][n][2]); p[3]=(short)f2bf(hn[m][n][3]);
        *(short4v*)&At[row*136 + col] = p;   // At reads done (GEMM-O over)
      }
    }
  }
  __syncthreads();

  // ---- GEMM1: Z = relu(Hn @ W_in^T + b_in) ----
  f32x4 acc1[2][8] = {};
  #pragma unroll
  for (int ks = 0; ks < 4; ++ks) {
    #pragma unroll
    for (int p = 0; p < 8; ++p)
      gload16(Wi2 + (size_t)ks*16384 + (tid + p*256)*8, &Bst[(tid + p*256)*8]);
    asm volatile("s_waitcnt vmcnt(0)" ::: "memory");
    __syncthreads();

    short8v a0 = *(const short8v*)&At[lm*136      + ks*32 + lgp*8];
    short8v a1 = *(const short8v*)&At[(16+lm)*136 + ks*32 + lgp*8];
    #pragma unroll
    for (int n = 0; n < 8; ++n) {
      short8v b = *(const short8v*)&Bst[((wave*8 + n)*64 + lane)*8];
      acc1[0][n] = __builtin_amdgcn_mfma_f32_16x16x32_bf16(b, a0, acc1[0][n], 0, 0, 0);
      acc1[1][n] = __builtin_amdgcn_mfma_f32_16x16x32_bf16(b, a1, acc1[1][n], 0, 0, 0);
    }
    __syncthreads();
  }

  #pragma unroll
  for (int m = 0; m < 2; ++m) {
    int row = m*16 + lm;
    #pragma unroll
    for (int n = 0; n < 8; ++n) {
      int col = (wave*8 + n)*16 + lgp*4;
      float4 bv = *(const float4*)&bin[col];
      short4v p;
      p[0]=(short)f2bf(fmaxf(acc1[m][n][0] + bv.x, 0.f));
      p[1]=(short)f2bf(fmaxf(acc1[m][n][1] + bv.y, 0.f));
      p[2]=(short)f2bf(fmaxf(acc1[m][n][2] + bv.z, 0.f));
      p[3]=(short)f2bf(fmaxf(acc1[m][n][3] + bv.w, 0.f));
      *(short4v*)&Zs[row*520 + col] = p;
    }
  }
  __syncthreads();

  // ---- GEMM2: Y = Z @ W_out^T (K=512, 8 stages x 2 ks) ----
  f32x4 acc2[2][2] = {};
  #pragma unroll
  for (int ks2 = 0; ks2 < 8; ++ks2) {
    #pragma unroll
    for (int p = 0; p < 4; ++p)
      gload16(Wo2 + (size_t)ks2*8192 + (tid + p*256)*8, &Bst[(tid + p*256)*8]);
    asm volatile("s_waitcnt vmcnt(0)" ::: "memory");
    __syncthreads();

    #pragma unroll
    for (int s = 0; s < 2; ++s) {
      int ks = ks2*2 + s;
      short8v a0 = *(const short8v*)&Zs[lm*520      + ks*32 + lgp*8];
      short8v a1 = *(const short8v*)&Zs[(16+lm)*520 + ks*32 + lgp*8];
      #pragma unroll
      for (int n = 0; n < 2; ++n) {
        short8v b = *(const short8v*)&Bst[(s*4096) + ((wave*2 + n)*64 + lane)*8];
        acc2[0][n] = __builtin_amdgcn_mfma_f32_16x16x32_bf16(b, a0, acc2[0][n], 0, 0, 0);
        acc2[1][n] = __builtin_amdgcn_mfma_f32_16x16x32_bf16(b, a1, acc2[1][n], 0, 0, 0);
      }
    }
    __syncthreads();
  }

  // ---- x2 = Y + b_out + Hn(regs); LN1; mask; store ----
  {
    f32x4 x[2][2];
    float s1r[2] = {0.f, 0.f}, s2r[2] = {0.f, 0.f};
    #pragma unroll
    for (int m = 0; m < 2; ++m) {
      #pragma unroll
      for (int n = 0; n < 2; ++n) {
        int col = (wave*2 + n)*16 + lgp*4;
        float4 bo = *(const float4*)&b_out[col];
        x[m][n][0] = acc2[m][n][0] + bo.x + hn[m][n][0];
        x[m][n][1] = acc2[m][n][1] + bo.y + hn[m][n][1];
        x[m][n][2] = acc2[m][n][2] + bo.z + hn[m][n][2];
        x[m][n][3] = acc2[m][n][3] + bo.w + hn[m][n][3];
        #pragma unroll
        for (int r = 0; r < 4; ++r) {
          s1r[m] += x[m][n][r];
          s2r[m] += x[m][n][r]*x[m][n][r];
        }
      }
    }
    #pragma unroll
    for (int m = 0; m < 2; ++m) {
      s1r[m] += __shfl_xor(s1r[m], 16); s2r[m] += __shfl_xor(s2r[m], 16);
      s1r[m] += __shfl_xor(s1r[m], 32); s2r[m] += __shfl_xor(s2r[m], 32);
    }
    if (lgp == 0) {
      part[(lm*4      + wave)*2 + 0] = s1r[0];
      part[(lm*4      + wave)*2 + 1] = s2r[0];
      part[((16+lm)*4 + wave)*2 + 0] = s1r[1];
      part[((16+lm)*4 + wave)*2 + 1] = s2r[1];
    }
    __syncthreads();
    if (tid < 32) {
      float s1 = 0.f, s2 = 0.f;
      #pragma unroll
      for (int w = 0; w < 4; ++w) { s1 += part[(tid*4+w)*2]; s2 += part[(tid*4+w)*2+1]; }
      float mu  = s1*(1.f/128.f);
      float var = (s2 - 128.f*mu*mu)*(1.f/127.f);
      red[tid*2]   = mu;
      red[tid*2+1] = 1.f/(sqrtf(var+LN_EPS)+LN_EPS);
    }
    __syncthreads();
    #pragma unroll
    for (int m = 0; m < 2; ++m) {
      int row = m*16 + lm;
      float mu = red[row*2], inv = red[row*2+1];
      float mv = mask_v[tok0 + row];
      #pragma unroll
      for (int n = 0; n < 2; ++n) {
        int col = (wave*2 + n)*16 + lgp*4;
        float4 g = *(const float4*)&gain1[col];
        float4 b = *(const float4*)&bias1[col];
        float4 y;
        y.x = mv*(g.x*(x[m][n][0]-mu)*inv + b.x);
        y.y = mv*(g.y*(x[m][n][1]-mu)*inv + b.y);
        y.z = mv*(g.z*(x[m][n][2]-mu)*inv + b.z);
        y.w = mv*(g.w*(x[m][n][3]-mu)*inv + b.w);
        *(float4*)&out[(size_t)(tok0+row)*TH + col] = y;
      }
    }
  }
}

// ---------------------------------------------------------------------------
extern "C" void kernel_launch(void* const* d_in, const int* in_sizes, int n_in,
                              void* d_out, int out_size, void* d_ws, size_t ws_size,
                              hipStream_t stream)
{
  const float* h_v         = (const float*)d_in[0];
  const float* h_e         = (const float*)d_in[1];
  const float* mask_v      = (const float*)d_in[2];
  const float* mask_attend = (const float*)d_in[3];
  const float* W_Q   = (const float*)d_in[4];
  const float* W_K   = (const float*)d_in[5];
  const float* W_V   = (const float*)d_in[6];
  const float* W_O   = (const float*)d_in[7];
  const float* gain0 = (const float*)d_in[8];
  const float* bias0 = (const float*)d_in[9];
  const float* gain1 = (const float*)d_in[10];
  const float* bias1 = (const float*)d_in[11];
  const float* W_in  = (const float*)d_in[12];
  const float* b_in  = (const float*)d_in[13];
  const float* W_out = (const float*)d_in[14];
  const float* b_out = (const float*)d_in[15];

  float* out = (float*)d_out;
  char* ws = (char*)d_ws;
  unsigned short* Wc2 = (unsigned short*)ws;               //  131,072 B
  unsigned short* Wq2 = (unsigned short*)(ws + 131072);    //   32,768 B
  unsigned short* Wp2 = (unsigned short*)(ws + 163840);    //   32,768 B
  unsigned short* Wi2 = (unsigned short*)(ws + 196608);    //  131,072 B
  unsigned short* Wo2 = (unsigned short*)(ws + 327680);    //  131,072 B
  float* ul = (float*)(ws + 458752);                       // 4,096,000 B

  conv_weights_kernel<<<896, 256, 0, stream>>>(W_K, W_V, W_Q, W_O, W_in, W_out,
                                               Wc2, Wq2, Wp2, Wi2, Wo2);
  kvattn_kernel<<<NTOK/4, 512, 0, stream>>>(h_e, Wc2, Wq2, h_v, mask_attend, ul);
  ffn_all_kernel<<<NTOK/32, 256, 0, stream>>>(ul, Wp2, h_v, gain0, bias0,
                                              Wi2, Wo2, b_in, b_out,
                                              gain1, bias1, mask_v, out);
}

// Round 11
// 79.174 us; speedup vs baseline: 1.3185x; 1.0221x over previous
//
#include <hip/hip_runtime.h>
#include <math.h>

#define TK 30
#define TH 128
#define TNIN 256
#define TDFF 512
#define NTOK 8000
#define ROWP 264   // KVs row stride in u16

typedef __attribute__((ext_vector_type(8))) short short8v;
typedef __attribute__((ext_vector_type(4))) short short4v;
typedef __attribute__((ext_vector_type(4))) float f32x4;

constexpr float LN_EPS = 1e-6f;
constexpr float NEG_INF = -3.402823466e38f;
constexpr float INV_SQRT_D = 0.17677669529663687f;  // 1/sqrt(32)

static __device__ __forceinline__ unsigned short f2bf(float f) {
  unsigned u = __float_as_uint(f);
  u = u + 0x7fffu + ((u >> 16) & 1u);
  return (unsigned short)(u >> 16);
}
static __device__ __forceinline__ float bf2f(unsigned short s) {
  return __uint_as_float(((unsigned)s) << 16);
}
static __device__ __forceinline__ void gload16(const void* gsrc, void* ldst) {
  __builtin_amdgcn_global_load_lds(
      (const __attribute__((address_space(1))) unsigned int*)gsrc,
      (__attribute__((address_space(3))) unsigned int*)ldst, 16, 0, 0);
}

// ---------------------------------------------------------------------------
// K0: weight prep (verbatim R10, verified). Frag-linear bf16:
//   elem ((ks*NF + n)*64 + lane)*8 + j = W[n*16+(lane&15)][ks*32+(lane>>4)*8+j]
// ---------------------------------------------------------------------------
__global__ void conv_weights_kernel(const float* __restrict__ W_K,
                                    const float* __restrict__ W_V,
                                    const float* __restrict__ W_Q,
                                    const float* __restrict__ W_O,
                                    const float* __restrict__ W_in,
                                    const float* __restrict__ W_out,
                                    unsigned short* __restrict__ Wc2,
                                    unsigned short* __restrict__ Wq2,
                                    unsigned short* __restrict__ Wp2,
                                    unsigned short* __restrict__ Wi2,
                                    unsigned short* __restrict__ Wo2)
{
  int idx = blockIdx.x * 256 + threadIdx.x;   // 0..229375
  if (idx < 65536) {
    int e = idx >> 3, j = idx & 7;
    int kk = e >> 10, n = (e >> 6) & 15, lane = e & 63;
    int r = n*16 + (lane & 15);
    int c = kk*32 + (lane >> 4)*8 + j;
    float v = (r < TH) ? W_K[(size_t)r*TNIN + c] : W_V[(size_t)(r-TH)*TNIN + c];
    Wc2[idx] = f2bf(v);
  } else if (idx < 81920) {
    int i2 = idx - 65536;
    int e = i2 >> 3, j = i2 & 7;
    int kk = e >> 9, n = (e >> 6) & 7, lane = e & 63;
    int r = n*16 + (lane & 15);
    int c = kk*32 + (lane >> 4)*8 + j;
    Wq2[i2] = f2bf(W_Q[(size_t)r*TH + c]);
  } else if (idx < 98304) {
    int ip = idx - 81920;
    int e = ip >> 3, j = ip & 7;
    int kk = e >> 9, n = (e >> 6) & 7, lane = e & 63;
    int r = n*16 + (lane & 15);
    int c = kk*32 + (lane >> 4)*8 + j;
    Wp2[ip] = f2bf(W_O[(size_t)r*TH + c]);
  } else if (idx < 163840) {
    int i3 = idx - 98304;
    int e = i3 >> 3, j = i3 & 7;
    int ks = e >> 11, n = (e >> 6) & 31, lane = e & 63;
    int r = n*16 + (lane & 15);
    int c = ks*32 + (lane >> 4)*8 + j;
    Wi2[i3] = f2bf(W_in[(size_t)r*TH + c]);
  } else {
    int i4 = idx - 163840;
    int e = i4 >> 3, j = i4 & 7;
    int ks = e >> 9, n = (e >> 6) & 7, lane = e & 63;
    int r = n*16 + (lane & 15);
    int c = ks*32 + (lane >> 4)*8 + j;
    Wo2[i4] = f2bf(W_out[(size_t)r*TDFF + c]);
  }
}

// ---------------------------------------------------------------------------
// K1: fused Q-proj + KV-GEMM + attention core (R10 structure, verified).
// R11: s_setprio(1) around the MFMA cluster (T5: 2 blocks/CU at different
// phases -> wave-role diversity -> scheduler can favor MFMA waves).
// ---------------------------------------------------------------------------
__global__ __launch_bounds__(512, 4) void kvattn_kernel(
    const float* __restrict__ A, const unsigned short* __restrict__ Wc2,
    const unsigned short* __restrict__ Wq2, const float* __restrict__ h_v,
    const float* __restrict__ mask_attend, float* __restrict__ ul)
{
  const int tid  = threadIdx.x;
  const int wave = tid >> 6;
  const int lane = tid & 63;
  const int lm   = lane & 15;
  const int lgp  = lane >> 4;
  const int mh   = wave >> 2;   // 0..1
  const int nq   = wave & 3;    // 0..3
  const int bn0  = blockIdx.x * 4;

  __shared__ __align__(16) char smem[73728];
  unsigned short* Bl  = (unsigned short*)smem;          // [3][8192]   0..49152
  unsigned short* Al  = (unsigned short*)(smem + 49152);// [2][128][40] ..69632
  unsigned short* KVs = (unsigned short*)smem;          // [128][264] overlay 0..67584
  float* att = (float*)(smem + 67584);                  // [4][4][32] (Al tail, dead)
  float* hvp = (float*)(smem + 69632);                  // [4][128] f32
  float* qvp = (float*)(smem + 71680);                  // [4][128] f32

  // ---- prologue extras: h_v to LDS (visible after first loop barrier) ----
  if (tid < 128) {
    int tok = tid >> 5, q = tid & 31;
    *(float4*)&hvp[tok*128 + q*4] = *(const float4*)&h_v[(size_t)(bn0 + tok)*TH + q*4];
  }

  const int rowa = tid >> 2, cga = tid & 3;
  const int rowc = (rowa > 119) ? 119 : rowa;
  const float* aptr = A + ((size_t)blockIdx.x*120 + rowc)*TNIN + cga*8;

  #define ISSUE_B(K)                                                             \
    { gload16(Wc2 + (size_t)(K)*8192 + tid*8,       &Bl[((K)%3)*8192 + tid*8]);  \
      gload16(Wc2 + (size_t)(K)*8192 + (tid+512)*8, &Bl[((K)%3)*8192 + (tid+512)*8]); }

  #define WRITE_A(K, S)                                                     \
    { short8v w;                                                            \
      w[0]=(short)f2bf(ra[S][0].x); w[1]=(short)f2bf(ra[S][0].y);           \
      w[2]=(short)f2bf(ra[S][0].z); w[3]=(short)f2bf(ra[S][0].w);           \
      w[4]=(short)f2bf(ra[S][1].x); w[5]=(short)f2bf(ra[S][1].y);           \
      w[6]=(short)f2bf(ra[S][1].z); w[7]=(short)f2bf(ra[S][1].w);           \
      *(short8v*)&Al[(((K)&1)*128 + rowa)*40 + cga*8] = w; }

  float4 ra[3][2];
  f32x4 acc[4][4] = {};

  // prologue: rA(0); B(0); B(1); rA(1); rA(2); write A(0)
  ra[0][0] = *(const float4*)(aptr + 0);
  ra[0][1] = *(const float4*)(aptr + 4);
  ISSUE_B(0);
  ISSUE_B(1);
  ra[1][0] = *(const float4*)(aptr + 32);
  ra[1][1] = *(const float4*)(aptr + 36);
  ra[2][0] = *(const float4*)(aptr + 64);
  ra[2][1] = *(const float4*)(aptr + 68);
  WRITE_A(0, 0);

  #pragma unroll
  for (int k = 0; k < 8; ++k) {
    if (k == 7)      asm volatile("s_waitcnt vmcnt(0)" ::: "memory");
    else if (k == 6) asm volatile("s_waitcnt vmcnt(4)" ::: "memory");
    else             asm volatile("s_waitcnt vmcnt(6)" ::: "memory");
    __builtin_amdgcn_s_barrier();

    if (k < 6) ISSUE_B(k+2);
    if (k < 5) {
      ra[k%3][0] = *(const float4*)(aptr + (k+3)*32);
      ra[k%3][1] = *(const float4*)(aptr + (k+3)*32 + 4);
    }

    short8v af[4];
    #pragma unroll
    for (int m = 0; m < 4; ++m)
      af[m] = *(const short8v*)&Al[((k&1)*128 + mh*64 + m*16 + lm)*40 + lgp*8];

    __builtin_amdgcn_s_setprio(1);
    #pragma unroll
    for (int n = 0; n < 4; ++n) {
      short8v b = *(const short8v*)&Bl[(k%3)*8192 + ((nq*4 + n)*64 + lane)*8];
      #pragma unroll
      for (int m = 0; m < 4; ++m)
        acc[m][n] = __builtin_amdgcn_mfma_f32_16x16x32_bf16(b, af[m], acc[m][n], 0, 0, 0);
    }
    __builtin_amdgcn_s_setprio(0);

    if (k < 7) WRITE_A(k+1, (k+1)%3);
  }
  #undef ISSUE_B
  #undef WRITE_A

  __syncthreads();   // all Bl/Al reads done before KVs overlay

  // ---- C writeout (verified swapped-operand mapping) ----
  #pragma unroll
  for (int m = 0; m < 4; ++m) {
    int row = mh*64 + m*16 + lm;
    #pragma unroll
    for (int n = 0; n < 4; ++n) {
      int col = nq*64 + n*16 + lgp*4;
      short4v p;
      p[0]=(short)f2bf(acc[m][n][0]); p[1]=(short)f2bf(acc[m][n][1]);
      p[2]=(short)f2bf(acc[m][n][2]); p[3]=(short)f2bf(acc[m][n][3]);
      *(short4v*)&KVs[row*ROWP + col] = p;
    }
  }

  // ---- Q = h_v @ W_Q^T (acc dead; wq loaded here from L2) ----
  {
    f32x4 qacc = {};
    const int tokc = (lm < 4) ? lm : 3;
    #pragma unroll
    for (int ks = 0; ks < 4; ++ks) {
      short8v wq = *(const short8v*)(Wq2 + ((size_t)(ks*8 + wave)*64 + lane)*8);
      const float* hp = hvp + tokc*128 + ks*32 + lgp*8;
      float4 lo = *(const float4*)hp;
      float4 hi = *(const float4*)(hp + 4);
      short8v ha;
      ha[0]=(short)f2bf(lo.x); ha[1]=(short)f2bf(lo.y);
      ha[2]=(short)f2bf(lo.z); ha[3]=(short)f2bf(lo.w);
      ha[4]=(short)f2bf(hi.x); ha[5]=(short)f2bf(hi.y);
      ha[6]=(short)f2bf(hi.z); ha[7]=(short)f2bf(hi.w);
      qacc = __builtin_amdgcn_mfma_f32_16x16x32_bf16(wq, ha, qacc, 0, 0, 0);
    }
    if (lm < 4) *(f32x4*)&qvp[lm*128 + wave*16 + lgp*4] = qacc;
  }
  __syncthreads();   // KVs + qvp visible

  // ---- logits + masked softmax ----
  {
    int tok = tid >> 7, h = (tid >> 5) & 3, k = tid & 31;
    int gtok = bn0 + tok;
    float s = 0.f;
    float ma = 0.f;
    if (k < TK) {
      const float* qp = &qvp[tok*128 + h*32];
      const unsigned short* kp = &KVs[(tok*TK + k)*ROWP + h*32];
      #pragma unroll
      for (int j = 0; j < 4; ++j) {
        short8v kf = *(const short8v*)(kp + j*8);
        float4 qa = *(const float4*)(qp + j*8);
        float4 qb = *(const float4*)(qp + j*8 + 4);
        s += qa.x*bf2f((unsigned short)kf[0]) + qa.y*bf2f((unsigned short)kf[1])
           + qa.z*bf2f((unsigned short)kf[2]) + qa.w*bf2f((unsigned short)kf[3])
           + qb.x*bf2f((unsigned short)kf[4]) + qb.y*bf2f((unsigned short)kf[5])
           + qb.z*bf2f((unsigned short)kf[6]) + qb.w*bf2f((unsigned short)kf[7]);
      }
      ma = mask_attend[(size_t)gtok*TK + k];
    }
    bool ok = (k < TK) && (ma > 0.f);
    float val = ok ? s * INV_SQRT_D : NEG_INF;
    float mm = val;
    #pragma unroll
    for (int d = 16; d >= 1; d >>= 1) mm = fmaxf(mm, __shfl_xor(mm, d, 32));
    float e = ok ? expf(val - mm) : 0.f;
    float ss = e;
    #pragma unroll
    for (int d = 16; d >= 1; d >>= 1) ss += __shfl_xor(ss, d, 32);
    att[(tok*4 + h)*32 + k] = e / ss;
  }
  __syncthreads();

  // ---- PV ----
  {
    int tok = tid >> 7, c = tid & 127;
    int gtok = bn0 + tok;
    const float* ar = &att[(tok*4 + (c >> 5))*32];
    const unsigned short* vb = &KVs[tok*TK*ROWP + TH + c];
    float u = 0.f;
    #pragma unroll
    for (int k = 0; k < TK; ++k)
      u += ar[k] * bf2f(vb[k*ROWP]);
    ul[(size_t)gtok*TH + c] = u;
  }
}

// ---------------------------------------------------------------------------
// K2: ffn_all (R10 math, verified) + R11 pipelined weight staging.
// Grid 250 -> 1 block/CU (grid-limited), so stage drains were fully exposed;
// now: per iter [vmcnt(0); barrier; issue next stage; compute] -- the MFMA
// phase covers the next stage's L2 latency. LDS 143 KB (free at 1 block/CU).
// ---------------------------------------------------------------------------
__global__ __launch_bounds__(256) void ffn_all_kernel(
    const float* __restrict__ ul, const unsigned short* __restrict__ Wp2,
    const float* __restrict__ h_v,
    const float* __restrict__ gain0, const float* __restrict__ bias0,
    const unsigned short* __restrict__ Wi2, const unsigned short* __restrict__ Wo2,
    const float* __restrict__ b_in, const float* __restrict__ b_out,
    const float* __restrict__ gain1, const float* __restrict__ bias1,
    const float* __restrict__ mask_v, float* __restrict__ out)
{
  const int tid  = threadIdx.x;
  const int tok0 = blockIdx.x * 32;
  const int wave = tid >> 6;
  const int lane = tid & 63;
  const int lm   = lane & 15;
  const int lgp  = lane >> 4;

  __shared__ __align__(16) char smem[143616];
  unsigned short* Wp  = (unsigned short*)smem;            // 32 KB  GEMM-O weights
  unsigned short* Wst = (unsigned short*)(smem + 32768);  // 64 KB  dbuf arena
  unsigned short* At  = (unsigned short*)(smem + 98304);  // [32][136] bf16
  unsigned short* Zs  = (unsigned short*)(smem + 107008); // [32][520] bf16
  float* bin  = (float*)(smem + 140288);                  // [512]
  float* part = (float*)(smem + 142336);                  // [32][4][2]
  float* red  = (float*)(smem + 143360);                  // [32][2]

  // ---- prologue: At <- bf16(ul), bin; issue Wp (8) then W1(0) (8) ----
  for (int t = tid; t < 1024; t += 256) {
    int row = t >> 5, q = t & 31;
    float4 v = *(const float4*)&ul[(size_t)(tok0+row)*TH + q*4];
    short4v w;
    w[0]=(short)f2bf(v.x); w[1]=(short)f2bf(v.y);
    w[2]=(short)f2bf(v.z); w[3]=(short)f2bf(v.w);
    *(short4v*)&At[row*136 + q*4] = w;
  }
  if (tid < 128) *(float4*)&bin[tid*4] = *(const float4*)&b_in[tid*4];
  #pragma unroll
  for (int p = 0; p < 8; ++p)
    gload16(Wp2 + (size_t)(tid + p*256)*8, &Wp[(tid + p*256)*8]);
  #pragma unroll
  for (int p = 0; p < 8; ++p)   // W1 stage 0 -> Wst buf0 (in flight through GEMM-O)
    gload16(Wi2 + (size_t)(tid + p*256)*8, &Wst[(tid + p*256)*8]);

  asm volatile("s_waitcnt vmcnt(8)" ::: "memory");  // Wp done (W1_0 may remain)
  __syncthreads();

  // ---- GEMM-O: dh = ul @ W_O^T ----
  f32x4 acco[2][2] = {};
  #pragma unroll
  for (int ks = 0; ks < 4; ++ks) {
    short8v a0 = *(const short8v*)&At[lm*136      + ks*32 + lgp*8];
    short8v a1 = *(const short8v*)&At[(16+lm)*136 + ks*32 + lgp*8];
    #pragma unroll
    for (int n = 0; n < 2; ++n) {
      short8v b = *(const short8v*)&Wp[((size_t)(ks*8 + wave*2 + n)*64 + lane)*8];
      acco[0][n] = __builtin_amdgcn_mfma_f32_16x16x32_bf16(b, a0, acco[0][n], 0, 0, 0);
      acco[1][n] = __builtin_amdgcn_mfma_f32_16x16x32_bf16(b, a1, acco[1][n], 0, 0, 0);
    }
  }

  // ---- x = dh + h_v ; LN0 ; Hn -> regs + At(bf16) ----
  f32x4 hn[2][2];
  {
    f32x4 x[2][2];
    float s1r[2] = {0.f, 0.f}, s2r[2] = {0.f, 0.f};
    #pragma unroll
    for (int m = 0; m < 2; ++m) {
      int row = m*16 + lm;
      #pragma unroll
      for (int n = 0; n < 2; ++n) {
        int col = (wave*2 + n)*16 + lgp*4;
        float4 hv = *(const float4*)&h_v[(size_t)(tok0+row)*TH + col];
        x[m][n][0] = acco[m][n][0] + hv.x;
        x[m][n][1] = acco[m][n][1] + hv.y;
        x[m][n][2] = acco[m][n][2] + hv.z;
        x[m][n][3] = acco[m][n][3] + hv.w;
        #pragma unroll
        for (int r = 0; r < 4; ++r) {
          s1r[m] += x[m][n][r];
          s2r[m] += x[m][n][r]*x[m][n][r];
        }
      }
    }
    #pragma unroll
    for (int m = 0; m < 2; ++m) {
      s1r[m] += __shfl_xor(s1r[m], 16); s2r[m] += __shfl_xor(s2r[m], 16);
      s1r[m] += __shfl_xor(s1r[m], 32); s2r[m] += __shfl_xor(s2r[m], 32);
    }
    if (lgp == 0) {
      part[(lm*4      + wave)*2 + 0] = s1r[0];
      part[(lm*4      + wave)*2 + 1] = s2r[0];
      part[((16+lm)*4 + wave)*2 + 0] = s1r[1];
      part[((16+lm)*4 + wave)*2 + 1] = s2r[1];
    }
    __syncthreads();
    if (tid < 32) {
      float s1 = 0.f, s2 = 0.f;
      #pragma unroll
      for (int w = 0; w < 4; ++w) { s1 += part[(tid*4+w)*2]; s2 += part[(tid*4+w)*2+1]; }
      float mu  = s1*(1.f/128.f);
      float var = (s2 - 128.f*mu*mu)*(1.f/127.f);
      red[tid*2]   = mu;
      red[tid*2+1] = 1.f/(sqrtf(var+LN_EPS)+LN_EPS);
    }
    __syncthreads();
    #pragma unroll
    for (int m = 0; m < 2; ++m) {
      int row = m*16 + lm;
      float mu = red[row*2], inv = red[row*2+1];
      #pragma unroll
      for (int n = 0; n < 2; ++n) {
        int col = (wave*2 + n)*16 + lgp*4;
        float4 g = *(const float4*)&gain0[col];
        float4 b = *(const float4*)&bias0[col];
        hn[m][n][0] = g.x*(x[m][n][0]-mu)*inv + b.x;
        hn[m][n][1] = g.y*(x[m][n][1]-mu)*inv + b.y;
        hn[m][n][2] = g.z*(x[m][n][2]-mu)*inv + b.z;
        hn[m][n][3] = g.w*(x[m][n][3]-mu)*inv + b.w;
        short4v p;
        p[0]=(short)f2bf(hn[m][n][0]); p[1]=(short)f2bf(hn[m][n][1]);
        p[2]=(short)f2bf(hn[m][n][2]); p[3]=(short)f2bf(hn[m][n][3]);
        *(short4v*)&At[row*136 + col] = p;
      }
    }
  }

  // ---- GEMM1: Z = relu(Hn @ W_in^T + b_in); pipelined stages ----
  // per iter: vmcnt(0) [stage ks landed]; barrier [At/Hn + WAR safe];
  //           issue stage ks+1 (or W2 stage 0); compute ks.
  f32x4 acc1[2][8] = {};
  #pragma unroll
  for (int ks = 0; ks < 4; ++ks) {
    asm volatile("s_waitcnt vmcnt(0)" ::: "memory");
    __builtin_amdgcn_s_barrier();
    if (ks < 3) {
      #pragma unroll
      for (int p = 0; p < 8; ++p)
        gload16(Wi2 + (size_t)(ks+1)*16384 + (tid + p*256)*8,
                &Wst[((ks+1)&1)*16384 + (tid + p*256)*8]);
    } else {
      #pragma unroll
      for (int p = 0; p < 4; ++p)   // W2 stage 0 -> Wst shorts [0..8192)
        gload16(Wo2 + (size_t)(tid + p*256)*8, &Wst[(tid + p*256)*8]);
    }

    short8v a0 = *(const short8v*)&At[lm*136      + ks*32 + lgp*8];
    short8v a1 = *(const short8v*)&At[(16+lm)*136 + ks*32 + lgp*8];
    #pragma unroll
    for (int n = 0; n < 8; ++n) {
      short8v b = *(const short8v*)&Wst[(ks&1)*16384 + ((wave*8 + n)*64 + lane)*8];
      acc1[0][n] = __builtin_amdgcn_mfma_f32_16x16x32_bf16(b, a0, acc1[0][n], 0, 0, 0);
      acc1[1][n] = __builtin_amdgcn_mfma_f32_16x16x32_bf16(b, a1, acc1[1][n], 0, 0, 0);
    }
  }

  // Z writeout (ds_writes; made visible by GEMM2 iter0's barrier)
  #pragma unroll
  for (int m = 0; m < 2; ++m) {
    int row = m*16 + lm;
    #pragma unroll
    for (int n = 0; n < 8; ++n) {
      int col = (wave*8 + n)*16 + lgp*4;
      float4 bv = *(const float4*)&bin[col];
      short4v p;
      p[0]=(short)f2bf(fmaxf(acc1[m][n][0] + bv.x, 0.f));
      p[1]=(short)f2bf(fmaxf(acc1[m][n][1] + bv.y, 0.f));
      p[2]=(short)f2bf(fmaxf(acc1[m][n][2] + bv.z, 0.f));
      p[3]=(short)f2bf(fmaxf(acc1[m][n][3] + bv.w, 0.f));
      *(short4v*)&Zs[row*520 + col] = p;
    }
  }

  // ---- GEMM2: Y = Z @ W_out^T (8 stages x 2 sub-ks); pipelined ----
  f32x4 acc2[2][2] = {};
  #pragma unroll
  for (int ks2 = 0; ks2 < 8; ++ks2) {
    asm volatile("s_waitcnt vmcnt(0)" ::: "memory");
    __builtin_amdgcn_s_barrier();
    if (ks2 < 7) {
      #pragma unroll
      for (int p = 0; p < 4; ++p)
        gload16(Wo2 + (size_t)(ks2+1)*8192 + (tid + p*256)*8,
                &Wst[((ks2+1)&1)*8192 + (tid + p*256)*8]);
    }

    #pragma unroll
    for (int s = 0; s < 2; ++s) {
      int ks = ks2*2 + s;
      short8v a0 = *(const short8v*)&Zs[lm*520      + ks*32 + lgp*8];
      short8v a1 = *(const short8v*)&Zs[(16+lm)*520 + ks*32 + lgp*8];
      #pragma unroll
      for (int n = 0; n < 2; ++n) {
        short8v b = *(const short8v*)&Wst[(ks2&1)*8192 + s*4096 + ((wave*2 + n)*64 + lane)*8];
        acc2[0][n] = __builtin_amdgcn_mfma_f32_16x16x32_bf16(b, a0, acc2[0][n], 0, 0, 0);
        acc2[1][n] = __builtin_amdgcn_mfma_f32_16x16x32_bf16(b, a1, acc2[1][n], 0, 0, 0);
      }
    }
  }

  // ---- x2 = Y + b_out + Hn(regs); LN1; mask; store ----
  {
    f32x4 x[2][2];
    float s1r[2] = {0.f, 0.f}, s2r[2] = {0.f, 0.f};
    #pragma unroll
    for (int m = 0; m < 2; ++m) {
      #pragma unroll
      for (int n = 0; n < 2; ++n) {
        int col = (wave*2 + n)*16 + lgp*4;
        float4 bo = *(const float4*)&b_out[col];
        x[m][n][0] = acc2[m][n][0] + bo.x + hn[m][n][0];
        x[m][n][1] = acc2[m][n][1] + bo.y + hn[m][n][1];
        x[m][n][2] = acc2[m][n][2] + bo.z + hn[m][n][2];
        x[m][n][3] = acc2[m][n][3] + bo.w + hn[m][n][3];
        #pragma unroll
        for (int r = 0; r < 4; ++r) {
          s1r[m] += x[m][n][r];
          s2r[m] += x[m][n][r]*x[m][n][r];
        }
      }
    }
    #pragma unroll
    for (int m = 0; m < 2; ++m) {
      s1r[m] += __shfl_xor(s1r[m], 16); s2r[m] += __shfl_xor(s2r[m], 16);
      s1r[m] += __shfl_xor(s1r[m], 32); s2r[m] += __shfl_xor(s2r[m], 32);
    }
    if (lgp == 0) {
      part[(lm*4      + wave)*2 + 0] = s1r[0];
      part[(lm*4      + wave)*2 + 1] = s2r[0];
      part[((16+lm)*4 + wave)*2 + 0] = s1r[1];
      part[((16+lm)*4 + wave)*2 + 1] = s2r[1];
    }
    __syncthreads();
    if (tid < 32) {
      float s1 = 0.f, s2 = 0.f;
      #pragma unroll
      for (int w = 0; w < 4; ++w) { s1 += part[(tid*4+w)*2]; s2 += part[(tid*4+w)*2+1]; }
      float mu  = s1*(1.f/128.f);
      float var = (s2 - 128.f*mu*mu)*(1.f/127.f);
      red[tid*2]   = mu;
      red[tid*2+1] = 1.f/(sqrtf(var+LN_EPS)+LN_EPS);
    }
    __syncthreads();
    #pragma unroll
    for (int m = 0; m < 2; ++m) {
      int row = m*16 + lm;
      float mu = red[row*2], inv = red[row*2+1];
      float mv = mask_v[tok0 + row];
      #pragma unroll
      for (int n = 0; n < 2; ++n) {
        int col = (wave*2 + n)*16 + lgp*4;
        float4 g = *(const float4*)&gain1[col];
        float4 b = *(const float4*)&bias1[col];
        float4 y;
        y.x = mv*(g.x*(x[m][n][0]-mu)*inv + b.x);
        y.y = mv*(g.y*(x[m][n][1]-mu)*inv + b.y);
        y.z = mv*(g.z*(x[m][n][2]-mu)*inv + b.z);
        y.w = mv*(g.w*(x[m][n][3]-mu)*inv + b.w);
        *(float4*)&out[(size_t)(tok0+row)*TH + col] = y;
      }
    }
  }
}

// ---------------------------------------------------------------------------
extern "C" void kernel_launch(void* const* d_in, const int* in_sizes, int n_in,
                              void* d_out, int out_size, void* d_ws, size_t ws_size,
                              hipStream_t stream)
{
  const float* h_v         = (const float*)d_in[0];
  const float* h_e         = (const float*)d_in[1];
  const float* mask_v      = (const float*)d_in[2];
  const float* mask_attend = (const float*)d_in[3];
  const float* W_Q   = (const float*)d_in[4];
  const float* W_K   = (const float*)d_in[5];
  const float* W_V   = (const float*)d_in[6];
  const float* W_O   = (const float*)d_in[7];
  const float* gain0 = (const float*)d_in[8];
  const float* bias0 = (const float*)d_in[9];
  const float* gain1 = (const float*)d_in[10];
  const float* bias1 = (const float*)d_in[11];
  const float* W_in  = (const float*)d_in[12];
  const float* b_in  = (const float*)d_in[13];
  const float* W_out = (const float*)d_in[14];
  const float* b_out = (const float*)d_in[15];

  float* out = (float*)d_out;
  char* ws = (char*)d_ws;
  unsigned short* Wc2 = (unsigned short*)ws;               //  131,072 B
  unsigned short* Wq2 = (unsigned short*)(ws + 131072);    //   32,768 B
  unsigned short* Wp2 = (unsigned short*)(ws + 163840);    //   32,768 B
  unsigned short* Wi2 = (unsigned short*)(ws + 196608);    //  131,072 B
  unsigned short* Wo2 = (unsigned short*)(ws + 327680);    //  131,072 B
  float* ul = (float*)(ws + 458752);                       // 4,096,000 B

  conv_weights_kernel<<<896, 256, 0, stream>>>(W_K, W_V, W_Q, W_O, W_in, W_out,
                                               Wc2, Wq2, Wp2, Wi2, Wo2);
  kvattn_kernel<<<NTOK/4, 512, 0, stream>>>(h_e, Wc2, Wq2, h_v, mask_attend, ul);
  ffn_all_kernel<<<NTOK/32, 256, 0, stream>>>(ul, Wp2, h_v, gain0, bias0,
                                              Wi2, Wo2, b_in, b_out,
                                              gain1, bias1, mask_v, out);
}